// Round 5
// baseline (4718.200 us; speedup 1.0000x reference)
//
#include <hip/hip_runtime.h>

#define DEV_INLINE __device__ __forceinline__

static const int SCAN_B = 512;

DEV_INLINE int lower_bound_i(const int* __restrict__ a, int n, int v) {
    int lo = 0, hi = n;
    while (lo < hi) { int m = (lo + hi) >> 1; if (a[m] < v) lo = m + 1; else hi = m; }
    return lo;
}

// 4 consecutive input features (k rows of W) for 2 rows at once.
// W addresses are wave-uniform -> scalar loads; one weight feeds 2 FMAs.
DEV_INLINE void fma4_2(float (&h)[2][16], const float* __restrict__ wrow,
                       float4 a0, float4 a1) {
    const float x0[4] = {a0.x, a0.y, a0.z, a0.w};
    const float x1[4] = {a1.x, a1.y, a1.z, a1.w};
#pragma unroll
    for (int s = 0; s < 4; s++) {
#pragma unroll
        for (int j = 0; j < 16; j++) {
            float wv = wrow[s * 16 + j];
            h[0][j] = fmaf(x0[s], wv, h[0][j]);
            h[1][j] = fmaf(x1[s], wv, h[1][j]);
        }
    }
}

// h[2][16] += x[2][16] * W[16 x 16-wide rows with row stride STRIDE]
template<int STRIDE>
DEV_INLINE void dense16_2(float (&h)[2][16], const float* __restrict__ W,
                          const float (&xa)[16], const float (&xb)[16]) {
#pragma unroll
    for (int k = 0; k < 16; k++) {
#pragma unroll
        for (int j = 0; j < 16; j++) {
            float wv = W[k * STRIDE + j];
            h[0][j] = fmaf(xa[k], wv, h[0][j]);
            h[1][j] = fmaf(xb[k], wv, h[1][j]);
        }
    }
}

// ========================= CSR build (once per launch) ======================
__global__ void hist_kernel(const int* __restrict__ receivers, int n_edges,
                            int* __restrict__ cnt) {
    int i = blockIdx.x * blockDim.x + threadIdx.x;
    if (i < n_edges) atomicAdd(&cnt[receivers[i]], 1);
}

__global__ __launch_bounds__(SCAN_B)
void scan_block_kernel(const int* __restrict__ cnt, int n,
                       int* __restrict__ scan_tmp, int* __restrict__ blk_sum) {
    __shared__ int s[SCAN_B];
    int tid = threadIdx.x;
    int i = blockIdx.x * SCAN_B + tid;
    int v = (i < n) ? cnt[i] : 0;
    s[tid] = v;
    __syncthreads();
    for (int off = 1; off < SCAN_B; off <<= 1) {
        int t = (tid >= off) ? s[tid - off] : 0;
        __syncthreads();
        s[tid] += t;
        __syncthreads();
    }
    if (i < n) scan_tmp[i] = s[tid];
    if (tid == SCAN_B - 1) blk_sum[blockIdx.x] = s[tid];
}

__global__ __launch_bounds__(1024)
void scan_top_kernel(int* __restrict__ blk_sum, int nb, int* __restrict__ blk_off) {
    __shared__ int s[1024];
    int tid = threadIdx.x;
    int v = (tid < nb) ? blk_sum[tid] : 0;
    s[tid] = v;
    __syncthreads();
    for (int off = 1; off < 1024; off <<= 1) {
        int t = (tid >= off) ? s[tid - off] : 0;
        __syncthreads();
        s[tid] += t;
        __syncthreads();
    }
    if (tid < nb) blk_off[tid] = s[tid] - v;   // exclusive
}

__global__ __launch_bounds__(SCAN_B)
void scan_finalize_kernel(const int* __restrict__ cnt, const int* __restrict__ scan_tmp,
                          const int* __restrict__ blk_off, int n,
                          int* __restrict__ row_ptr, int* __restrict__ running) {
    int i = blockIdx.x * SCAN_B + threadIdx.x;
    if (i >= n) return;
    int incl = scan_tmp[i] + blk_off[i / SCAN_B];
    row_ptr[i + 1] = incl;
    running[i] = incl - cnt[i];
    if (i == 0) row_ptr[0] = 0;
}

__global__ void fill_kernel(const int* __restrict__ receivers, int n_edges,
                            int* __restrict__ running, int* __restrict__ col_idx) {
    int e = blockIdx.x * blockDim.x + threadIdx.x;
    if (e >= n_edges) return;
    int pos = atomicAdd(&running[receivers[e]], 1);
    col_idx[pos] = e;
}

// ---------------- Edge block: 112 -> 16 -> 16 -> 32, E=2, fused graph-sum ---
__global__ __launch_bounds__(256)
void edge_block_kernel(const float* __restrict__ edges_in,
                       const float* __restrict__ nodes_in,
                       const float* __restrict__ glob_in,
                       const int* __restrict__ senders,
                       const int* __restrict__ receivers,
                       const int* __restrict__ edge_gid,
                       const float* __restrict__ W1, const float* __restrict__ B1,
                       const float* __restrict__ W2, const float* __restrict__ B2,
                       const float* __restrict__ W3, const float* __restrict__ B3,
                       float* __restrict__ edges_out,
                       float* __restrict__ gsum_e,
                       int n_edges) {
    const int t = threadIdx.x;
    const int lane = t & 63;
    const int e0 = blockIdx.x * 512 + 2 * t;
    const int e1 = e0 + 1;
    const bool v0 = (e0 < n_edges), v1 = (e1 < n_edges);
    const int ea = min(e0, n_edges - 1), eb = min(e1, n_edges - 1);

    const int rr0 = receivers[ea], ss0 = senders[ea], gg0 = edge_gid[ea];
    const int rr1 = receivers[eb], ss1 = senders[eb], gg1 = edge_gid[eb];

    float h1[2][16];
#pragma unroll
    for (int j = 0; j < 16; j++) { h1[0][j] = B1[j]; h1[1][j] = B1[j]; }

    {   // 0..31: edge features
        const float4* pa = (const float4*)edges_in + (size_t)ea * 8;
        const float4* pb = (const float4*)edges_in + (size_t)eb * 8;
#pragma unroll
        for (int q = 0; q < 8; q++) fma4_2(h1, W1 + (q * 4) * 16, pa[q], pb[q]);
    }
    {   // 32..63: nodes[receiver]
        const float4* pa = (const float4*)nodes_in + (size_t)rr0 * 8;
        const float4* pb = (const float4*)nodes_in + (size_t)rr1 * 8;
#pragma unroll
        for (int q = 0; q < 8; q++) fma4_2(h1, W1 + (32 + q * 4) * 16, pa[q], pb[q]);
    }
    {   // 64..95: nodes[sender]
        const float4* pa = (const float4*)nodes_in + (size_t)ss0 * 8;
        const float4* pb = (const float4*)nodes_in + (size_t)ss1 * 8;
#pragma unroll
        for (int q = 0; q < 8; q++) fma4_2(h1, W1 + (64 + q * 4) * 16, pa[q], pb[q]);
    }
    {   // 96..111: globals[edge_gid]
        const float4* pa = (const float4*)glob_in + (size_t)gg0 * 4;
        const float4* pb = (const float4*)glob_in + (size_t)gg1 * 4;
#pragma unroll
        for (int q = 0; q < 4; q++) fma4_2(h1, W1 + (96 + q * 4) * 16, pa[q], pb[q]);
    }

    float xa[16], xb[16];
#pragma unroll
    for (int j = 0; j < 16; j++) { xa[j] = fmaxf(h1[0][j], 0.0f); xb[j] = fmaxf(h1[1][j], 0.0f); }
    float h2[2][16];
#pragma unroll
    for (int j = 0; j < 16; j++) { h2[0][j] = B2[j]; h2[1][j] = B2[j]; }
    dense16_2<16>(h2, W2, xa, xb);

#pragma unroll
    for (int j = 0; j < 16; j++) { xa[j] = fmaxf(h2[0][j], 0.0f); xb[j] = fmaxf(h2[1][j], 0.0f); }

    const int gref = __shfl(gg0, 0);
    const bool uni = __all(((!v0) || gg0 == gref) && ((!v1) || gg1 == gref));

#pragma unroll
    for (int ph = 0; ph < 2; ph++) {
        float o[2][16];
#pragma unroll
        for (int j = 0; j < 16; j++) { o[0][j] = B3[ph * 16 + j]; o[1][j] = B3[ph * 16 + j]; }
        dense16_2<32>(o, W3 + ph * 16, xa, xb);

        if (v0) {
            float4* eo = (float4*)(edges_out + (size_t)e0 * 32 + ph * 16);
#pragma unroll
            for (int j4 = 0; j4 < 4; j4++)
                eo[j4] = make_float4(o[0][j4 * 4 + 0], o[0][j4 * 4 + 1],
                                     o[0][j4 * 4 + 2], o[0][j4 * 4 + 3]);
        }
        if (v1) {
            float4* eo = (float4*)(edges_out + (size_t)e1 * 32 + ph * 16);
#pragma unroll
            for (int j4 = 0; j4 < 4; j4++)
                eo[j4] = make_float4(o[1][j4 * 4 + 0], o[1][j4 * 4 + 1],
                                     o[1][j4 * 4 + 2], o[1][j4 * 4 + 3]);
        }

        // fused per-graph sum
        if (uni) {
            float s[16];
#pragma unroll
            for (int j = 0; j < 16; j++)
                s[j] = (v0 ? o[0][j] : 0.0f) + (v1 ? o[1][j] : 0.0f);
#pragma unroll
            for (int off = 32; off >= 1; off >>= 1)
#pragma unroll
                for (int j = 0; j < 16; j++) s[j] += __shfl_xor(s[j], off);
            if (lane == 0) {
#pragma unroll
                for (int j = 0; j < 16; j++)
                    atomicAdd(&gsum_e[gref * 32 + ph * 16 + j], s[j]);
            }
        } else {
            if (v0) {
#pragma unroll
                for (int j = 0; j < 16; j++)
                    atomicAdd(&gsum_e[gg0 * 32 + ph * 16 + j], o[0][j]);
            }
            if (v1) {
#pragma unroll
                for (int j = 0; j < 16; j++)
                    atomicAdd(&gsum_e[gg1 * 32 + ph * 16 + j], o[1][j]);
            }
        }
    }
}

// -------- Receiver aggregation via CSR gather: 8 lanes per node -------------
__global__ __launch_bounds__(256)
void agg_mean_kernel(const float* __restrict__ edges_data,
                     const int* __restrict__ col_idx,
                     const int* __restrict__ row_ptr,
                     float* __restrict__ agg_mean, int n_nodes) {
    int node = blockIdx.x * 32 + (threadIdx.x >> 3);
    int lane = threadIdx.x & 7;
    if (node >= n_nodes) return;
    int lo = row_ptr[node], hi = row_ptr[node + 1];
    float4 acc = make_float4(0.f, 0.f, 0.f, 0.f);
    for (int e = lo; e < hi; e++) {
        int idx = col_idx[e];
        float4 v = ((const float4*)(edges_data + (size_t)idx * 32))[lane];
        acc.x += v.x; acc.y += v.y; acc.z += v.z; acc.w += v.w;
    }
    float inv = 1.0f / fmaxf((float)(hi - lo), 1.0f);
    ((float4*)(agg_mean + (size_t)node * 32))[lane] =
        make_float4(acc.x * inv, acc.y * inv, acc.z * inv, acc.w * inv);
}

// ---------------- Node block: 80 -> 16 -> 16 -> 32, E=2 ---------------------
__global__ __launch_bounds__(256)
void node_block_kernel(const float* __restrict__ agg_mean,
                       const float* __restrict__ nodes_in,
                       const float* __restrict__ glob_in,
                       const int* __restrict__ node_gid,
                       const float* __restrict__ W1, const float* __restrict__ B1,
                       const float* __restrict__ W2, const float* __restrict__ B2,
                       const float* __restrict__ W3, const float* __restrict__ B3,
                       float* __restrict__ nodes_out,
                       int n_nodes) {
    const int t = threadIdx.x;
    const int n0 = blockIdx.x * 512 + 2 * t;
    const int n1 = n0 + 1;
    const bool v0 = (n0 < n_nodes), v1 = (n1 < n_nodes);
    const int na = min(n0, n_nodes - 1), nb = min(n1, n_nodes - 1);
    const int gg0 = node_gid[na], gg1 = node_gid[nb];

    float h1[2][16];
#pragma unroll
    for (int j = 0; j < 16; j++) { h1[0][j] = B1[j]; h1[1][j] = B1[j]; }

    {   // 0..31: mean of received edges (pre-averaged)
        const float4* pa = (const float4*)agg_mean + (size_t)na * 8;
        const float4* pb = (const float4*)agg_mean + (size_t)nb * 8;
#pragma unroll
        for (int q = 0; q < 8; q++) fma4_2(h1, W1 + (q * 4) * 16, pa[q], pb[q]);
    }
    {   // 32..63: nodes
        const float4* pa = (const float4*)nodes_in + (size_t)na * 8;
        const float4* pb = (const float4*)nodes_in + (size_t)nb * 8;
#pragma unroll
        for (int q = 0; q < 8; q++) fma4_2(h1, W1 + (32 + q * 4) * 16, pa[q], pb[q]);
    }
    {   // 64..79: globals[node_gid]
        const float4* pa = (const float4*)glob_in + (size_t)gg0 * 4;
        const float4* pb = (const float4*)glob_in + (size_t)gg1 * 4;
#pragma unroll
        for (int q = 0; q < 4; q++) fma4_2(h1, W1 + (64 + q * 4) * 16, pa[q], pb[q]);
    }

    float xa[16], xb[16];
#pragma unroll
    for (int j = 0; j < 16; j++) { xa[j] = fmaxf(h1[0][j], 0.0f); xb[j] = fmaxf(h1[1][j], 0.0f); }
    float h2[2][16];
#pragma unroll
    for (int j = 0; j < 16; j++) { h2[0][j] = B2[j]; h2[1][j] = B2[j]; }
    dense16_2<16>(h2, W2, xa, xb);

#pragma unroll
    for (int j = 0; j < 16; j++) { xa[j] = fmaxf(h2[0][j], 0.0f); xb[j] = fmaxf(h2[1][j], 0.0f); }

#pragma unroll
    for (int ph = 0; ph < 2; ph++) {
        float o[2][16];
#pragma unroll
        for (int j = 0; j < 16; j++) { o[0][j] = B3[ph * 16 + j]; o[1][j] = B3[ph * 16 + j]; }
        dense16_2<32>(o, W3 + ph * 16, xa, xb);

        if (v0) {
            float4* no = (float4*)(nodes_out + (size_t)n0 * 32 + ph * 16);
#pragma unroll
            for (int j4 = 0; j4 < 4; j4++)
                no[j4] = make_float4(o[0][j4 * 4 + 0], o[0][j4 * 4 + 1],
                                     o[0][j4 * 4 + 2], o[0][j4 * 4 + 3]);
        }
        if (v1) {
            float4* no = (float4*)(nodes_out + (size_t)n1 * 32 + ph * 16);
#pragma unroll
            for (int j4 = 0; j4 < 4; j4++)
                no[j4] = make_float4(o[1][j4 * 4 + 0], o[1][j4 * 4 + 1],
                                     o[1][j4 * 4 + 2], o[1][j4 * 4 + 3]);
        }
    }
}

// ---------------- Per-graph sums over sorted gid ranges (nodes) -------------
__global__ __launch_bounds__(256)
void graph_sum_kernel(const float* __restrict__ x, const int* __restrict__ gid,
                      int n_rows, float* __restrict__ sums, int splits) {
    int g = blockIdx.x / splits;
    int s = blockIdx.x % splits;
    int lo = lower_bound_i(gid, n_rows, g);
    int hi = lower_bound_i(gid, n_rows, g + 1);
    int len = hi - lo;
    int chunk = (len + splits - 1) / splits;
    int rlo = lo + s * chunk;
    int rhi = min(rlo + chunk, hi);

    int c = threadIdx.x & 31;
    int rg = threadIdx.x >> 5;   // 8 row-groups with 256 threads
    float acc = 0.0f;
    for (int r = rlo + rg; r < rhi; r += 8)
        acc += x[(size_t)r * 32 + c];

    __shared__ float red[256];
    red[threadIdx.x] = acc;
    __syncthreads();
    if (threadIdx.x < 32) {
        float ssum = 0.0f;
#pragma unroll
        for (int i = 0; i < 8; i++) ssum += red[i * 32 + threadIdx.x];
        atomicAdd(&sums[g * 32 + threadIdx.x], ssum);
    }
}

// ---------------- Global block: 80 -> 16 -> 16 -> 16 ------------------------
__global__ __launch_bounds__(64)
void global_block_kernel(const float* __restrict__ gsum_e,
                         const float* __restrict__ gsum_n,
                         const float* __restrict__ glob_in,
                         const int* __restrict__ edge_gid, int n_edges,
                         const int* __restrict__ node_gid, int n_nodes,
                         const float* __restrict__ W1, const float* __restrict__ B1,
                         const float* __restrict__ W2, const float* __restrict__ B2,
                         const float* __restrict__ W3, const float* __restrict__ B3,
                         float* __restrict__ glob_out, int n_graph) {
    const int g0 = threadIdx.x;
    const int g  = min(g0, n_graph - 1);

    int ecnt = lower_bound_i(edge_gid, n_edges, g + 1) - lower_bound_i(edge_gid, n_edges, g);
    int ncnt = lower_bound_i(node_gid, n_nodes, g + 1) - lower_bound_i(node_gid, n_nodes, g);
    float inv_e = 1.0f / fmaxf((float)ecnt, 1.0f);
    float inv_n = 1.0f / fmaxf((float)ncnt, 1.0f);

    float h1[16];
#pragma unroll
    for (int j = 0; j < 16; j++) h1[j] = B1[j];

    {
        float x[32];
#pragma unroll
        for (int q = 0; q < 8; q++) {
            float4 v = ((const float4*)gsum_e)[(size_t)g * 8 + q];
            x[q*4+0] = v.x * inv_e; x[q*4+1] = v.y * inv_e; x[q*4+2] = v.z * inv_e; x[q*4+3] = v.w * inv_e;
        }
#pragma unroll
        for (int k = 0; k < 32; k++)
#pragma unroll
            for (int j = 0; j < 16; j++) h1[j] = fmaf(x[k], W1[k * 16 + j], h1[j]);
#pragma unroll
        for (int q = 0; q < 8; q++) {
            float4 v = ((const float4*)gsum_n)[(size_t)g * 8 + q];
            x[q*4+0] = v.x * inv_n; x[q*4+1] = v.y * inv_n; x[q*4+2] = v.z * inv_n; x[q*4+3] = v.w * inv_n;
        }
#pragma unroll
        for (int k = 0; k < 32; k++)
#pragma unroll
            for (int j = 0; j < 16; j++) h1[j] = fmaf(x[k], W1[(32 + k) * 16 + j], h1[j]);
    }
    {
        float xg[16];
#pragma unroll
        for (int q = 0; q < 4; q++) {
            float4 v = ((const float4*)glob_in)[(size_t)g * 4 + q];
            xg[q*4+0] = v.x; xg[q*4+1] = v.y; xg[q*4+2] = v.z; xg[q*4+3] = v.w;
        }
#pragma unroll
        for (int k = 0; k < 16; k++)
#pragma unroll
            for (int j = 0; j < 16; j++) h1[j] = fmaf(xg[k], W1[(64 + k) * 16 + j], h1[j]);
    }

    float x2[16];
#pragma unroll
    for (int j = 0; j < 16; j++) x2[j] = fmaxf(h1[j], 0.0f);
    float h2[16];
#pragma unroll
    for (int j = 0; j < 16; j++) h2[j] = B2[j];
#pragma unroll
    for (int k = 0; k < 16; k++)
#pragma unroll
        for (int j = 0; j < 16; j++) h2[j] = fmaf(x2[k], W2[k * 16 + j], h2[j]);

    float x3[16];
#pragma unroll
    for (int j = 0; j < 16; j++) x3[j] = fmaxf(h2[j], 0.0f);
    float o[16];
#pragma unroll
    for (int j = 0; j < 16; j++) o[j] = B3[j];
#pragma unroll
    for (int k = 0; k < 16; k++)
#pragma unroll
        for (int j = 0; j < 16; j++) o[j] = fmaf(x3[k], W3[k * 16 + j], o[j]);

    if (g0 < n_graph) {
#pragma unroll
        for (int j = 0; j < 16; j++) glob_out[g0 * 16 + j] = o[j];
    }
}

extern "C" void kernel_launch(void* const* d_in, const int* in_sizes, int n_in,
                              void* d_out, int out_size, void* d_ws, size_t ws_size,
                              hipStream_t stream) {
    const float* d_nodes = (const float*)d_in[0];
    const float* d_edges = (const float*)d_in[1];
    const float* d_glob  = (const float*)d_in[2];
    const int* senders   = (const int*)d_in[3];
    const int* receivers = (const int*)d_in[4];
    const int* node_gid  = (const int*)d_in[5];
    const int* edge_gid  = (const int*)d_in[6];
    const float* e_w1 = (const float*)d_in[7];
    const float* e_b1 = (const float*)d_in[8];
    const float* e_w2 = (const float*)d_in[9];
    const float* e_b2 = (const float*)d_in[10];
    const float* e_w3 = (const float*)d_in[11];
    const float* e_b3 = (const float*)d_in[12];
    const float* n_w1 = (const float*)d_in[13];
    const float* n_b1 = (const float*)d_in[14];
    const float* n_w2 = (const float*)d_in[15];
    const float* n_b2 = (const float*)d_in[16];
    const float* n_w3 = (const float*)d_in[17];
    const float* n_b3 = (const float*)d_in[18];
    const float* g_w1 = (const float*)d_in[19];
    const float* g_b1 = (const float*)d_in[20];
    const float* g_w2 = (const float*)d_in[21];
    const float* g_b2 = (const float*)d_in[22];
    const float* g_w3 = (const float*)d_in[23];
    const float* g_b3 = (const float*)d_in[24];

    const int n_nodes = in_sizes[0] / 32;
    const int n_edges = in_sizes[1] / 32;
    const int n_graph = in_sizes[2] / 16;

    float* out_nodes = (float*)d_out;                        // n_nodes*32
    float* out_edges = out_nodes + (size_t)n_nodes * 32;     // n_edges*32
    float* out_glob  = out_edges + (size_t)n_edges * 32;     // n_graph*16

    float* ws = (float*)d_ws;
    float* ws_edges = ws;  ws += (size_t)n_edges * 32;
    float* ws_nodes = ws;  ws += (size_t)n_nodes * 32;
    float* agg_mean = ws;  ws += (size_t)n_nodes * 32;
    float* gA       = ws;  ws += (size_t)n_graph * 16;
    float* gB       = ws;  ws += (size_t)n_graph * 16;
    float* gsum_e   = ws;  ws += (size_t)n_graph * 32;
    float* gsum_n   = ws;  ws += (size_t)n_graph * 32;

    int* wi = (int*)ws;
    int* cnt      = wi;  wi += n_nodes;
    int* row_ptr  = wi;  wi += n_nodes + 1;
    int* running  = wi;  wi += n_nodes;
    int* scan_tmp = wi;  wi += n_nodes;
    int* col_idx  = wi;  wi += n_edges;
    int* blk_sum  = wi;  wi += 1024;
    int* blk_off  = wi;  wi += 1024;

    const int nblocks_scan = (n_nodes + SCAN_B - 1) / SCAN_B;

    // ---- CSR build (receivers constant across passes) ----
    hipMemsetAsync(cnt, 0, (size_t)n_nodes * sizeof(int), stream);
    hist_kernel<<<(n_edges + 255) / 256, 256, 0, stream>>>(receivers, n_edges, cnt);
    scan_block_kernel<<<nblocks_scan, SCAN_B, 0, stream>>>(cnt, n_nodes, scan_tmp, blk_sum);
    scan_top_kernel<<<1, 1024, 0, stream>>>(blk_sum, nblocks_scan, blk_off);
    scan_finalize_kernel<<<nblocks_scan, SCAN_B, 0, stream>>>(cnt, scan_tmp, blk_off,
                                                              n_nodes, row_ptr, running);
    fill_kernel<<<(n_edges + 255) / 256, 256, 0, stream>>>(receivers, n_edges, running, col_idx);

    const float* nodes_in = d_nodes;
    const float* edges_in = d_edges;
    const float* glob_in  = d_glob;

    for (int pass = 0; pass < 3; ++pass) {
        float* nodes_out; float* edges_out; float* glob_out;
        if (pass == 0)      { nodes_out = out_nodes; edges_out = out_edges; glob_out = gA; }
        else if (pass == 1) { nodes_out = ws_nodes;  edges_out = ws_edges;  glob_out = gB; }
        else                { nodes_out = out_nodes; edges_out = out_edges; glob_out = out_glob; }

        hipMemsetAsync(gsum_e, 0, (size_t)n_graph * 32 * sizeof(float), stream);
        hipMemsetAsync(gsum_n, 0, (size_t)n_graph * 32 * sizeof(float), stream);

        edge_block_kernel<<<(n_edges + 511) / 512, 256, 0, stream>>>(
            edges_in, nodes_in, glob_in, senders, receivers, edge_gid,
            e_w1, e_b1, e_w2, e_b2, e_w3, e_b3,
            edges_out, gsum_e, n_edges);

        agg_mean_kernel<<<(n_nodes + 31) / 32, 256, 0, stream>>>(
            edges_out, col_idx, row_ptr, agg_mean, n_nodes);

        node_block_kernel<<<(n_nodes + 511) / 512, 256, 0, stream>>>(
            agg_mean, nodes_in, glob_in, node_gid,
            n_w1, n_b1, n_w2, n_b2, n_w3, n_b3,
            nodes_out, n_nodes);

        graph_sum_kernel<<<n_graph * 4, 256, 0, stream>>>(nodes_out, node_gid, n_nodes, gsum_n, 4);

        global_block_kernel<<<1, 64, 0, stream>>>(
            gsum_e, gsum_n, glob_in, edge_gid, n_edges, node_gid, n_nodes,
            g_w1, g_b1, g_w2, g_b2, g_w3, g_b3,
            glob_out, n_graph);

        nodes_in = nodes_out;
        edges_in = edges_out;
        glob_in  = glob_out;
    }
}

// Round 6
// 922.811 us; speedup vs baseline: 5.1129x; 5.1129x over previous
//
#include <hip/hip_runtime.h>

#define DEV_INLINE __device__ __forceinline__

static const int SCAN_B = 512;

DEV_INLINE int lower_bound_i(const int* __restrict__ a, int n, int v) {
    int lo = 0, hi = n;
    while (lo < hi) { int m = (lo + hi) >> 1; if (a[m] < v) lo = m + 1; else hi = m; }
    return lo;
}

// h[0:16] += 4 features (a.x..a.w) * W rows (wave-uniform W -> scalar loads)
DEV_INLINE void fma4(float (&h)[16], const float* __restrict__ W, float4 a) {
#pragma unroll
    for (int j = 0; j < 16; j++) h[j] = fmaf(a.x, W[0 * 16 + j], h[j]);
#pragma unroll
    for (int j = 0; j < 16; j++) h[j] = fmaf(a.y, W[1 * 16 + j], h[j]);
#pragma unroll
    for (int j = 0; j < 16; j++) h[j] = fmaf(a.z, W[2 * 16 + j], h[j]);
#pragma unroll
    for (int j = 0; j < 16; j++) h[j] = fmaf(a.w, W[3 * 16 + j], h[j]);
}

// ========================= CSR build (once per launch) ======================
__global__ void hist_kernel(const int* __restrict__ receivers, int n_edges,
                            int* __restrict__ cnt) {
    int i = blockIdx.x * blockDim.x + threadIdx.x;
    if (i < n_edges) atomicAdd(&cnt[receivers[i]], 1);
}

__global__ __launch_bounds__(SCAN_B)
void scan_block_kernel(const int* __restrict__ cnt, int n,
                       int* __restrict__ scan_tmp, int* __restrict__ blk_sum) {
    __shared__ int s[SCAN_B];
    int tid = threadIdx.x;
    int i = blockIdx.x * SCAN_B + tid;
    int v = (i < n) ? cnt[i] : 0;
    s[tid] = v;
    __syncthreads();
    for (int off = 1; off < SCAN_B; off <<= 1) {
        int t = (tid >= off) ? s[tid - off] : 0;
        __syncthreads();
        s[tid] += t;
        __syncthreads();
    }
    if (i < n) scan_tmp[i] = s[tid];
    if (tid == SCAN_B - 1) blk_sum[blockIdx.x] = s[tid];
}

__global__ __launch_bounds__(1024)
void scan_top_kernel(int* __restrict__ blk_sum, int nb, int* __restrict__ blk_off) {
    __shared__ int s[1024];
    int tid = threadIdx.x;
    int v = (tid < nb) ? blk_sum[tid] : 0;
    s[tid] = v;
    __syncthreads();
    for (int off = 1; off < 1024; off <<= 1) {
        int t = (tid >= off) ? s[tid - off] : 0;
        __syncthreads();
        s[tid] += t;
        __syncthreads();
    }
    if (tid < nb) blk_off[tid] = s[tid] - v;   // exclusive
}

__global__ __launch_bounds__(SCAN_B)
void scan_finalize_kernel(const int* __restrict__ cnt, const int* __restrict__ scan_tmp,
                          const int* __restrict__ blk_off, int n,
                          int* __restrict__ row_ptr, int* __restrict__ running) {
    int i = blockIdx.x * SCAN_B + threadIdx.x;
    if (i >= n) return;
    int incl = scan_tmp[i] + blk_off[i / SCAN_B];
    row_ptr[i + 1] = incl;
    running[i] = incl - cnt[i];
    if (i == 0) row_ptr[0] = 0;
}

__global__ void fill_kernel(const int* __restrict__ receivers, int n_edges,
                            int* __restrict__ running, int* __restrict__ col_idx) {
    int e = blockIdx.x * blockDim.x + threadIdx.x;
    if (e >= n_edges) return;
    int pos = atomicAdd(&running[receivers[e]], 1);
    col_idx[pos] = e;
}

// ---------------- Edge block: 112 -> 16 -> 16 -> 32 -------------------------
// All 28 input float4 loads hoisted to the top (max memory-level parallelism);
// weights via wave-uniform scalar loads; masked store, no divergent return.
__global__ __launch_bounds__(256)
void edge_block_kernel(const float* __restrict__ edges_in,
                       const float* __restrict__ nodes_in,
                       const float* __restrict__ glob_in,
                       const int* __restrict__ senders,
                       const int* __restrict__ receivers,
                       const int* __restrict__ edge_gid,
                       const float* __restrict__ W1, const float* __restrict__ B1,
                       const float* __restrict__ W2, const float* __restrict__ B2,
                       const float* __restrict__ W3, const float* __restrict__ B3,
                       float* __restrict__ edges_out,
                       int n_edges) {
    const int e0 = blockIdx.x * 256 + threadIdx.x;
    const int e  = min(e0, n_edges - 1);

    const int rr = receivers[e], ss = senders[e], gg = edge_gid[e];

    const float4* pe = (const float4*)edges_in + (size_t)e  * 8;
    const float4* pr = (const float4*)nodes_in + (size_t)rr * 8;
    const float4* ps = (const float4*)nodes_in + (size_t)ss * 8;
    const float4* pg = (const float4*)glob_in  + (size_t)gg * 4;

    float4 xe[8], xr[8], xs[8], xg[4];
#pragma unroll
    for (int q = 0; q < 8; q++) xe[q] = pe[q];
#pragma unroll
    for (int q = 0; q < 8; q++) xr[q] = pr[q];
#pragma unroll
    for (int q = 0; q < 8; q++) xs[q] = ps[q];
#pragma unroll
    for (int q = 0; q < 4; q++) xg[q] = pg[q];

    float h1[16];
#pragma unroll
    for (int j = 0; j < 16; j++) h1[j] = B1[j];
#pragma unroll
    for (int q = 0; q < 8; q++) fma4(h1, W1 + (q * 4) * 16, xe[q]);
#pragma unroll
    for (int q = 0; q < 8; q++) fma4(h1, W1 + (32 + q * 4) * 16, xr[q]);
#pragma unroll
    for (int q = 0; q < 8; q++) fma4(h1, W1 + (64 + q * 4) * 16, xs[q]);
#pragma unroll
    for (int q = 0; q < 4; q++) fma4(h1, W1 + (96 + q * 4) * 16, xg[q]);

    float x2[16];
#pragma unroll
    for (int j = 0; j < 16; j++) x2[j] = fmaxf(h1[j], 0.0f);
    float h2[16];
#pragma unroll
    for (int j = 0; j < 16; j++) h2[j] = B2[j];
#pragma unroll
    for (int k = 0; k < 16; k++)
#pragma unroll
        for (int j = 0; j < 16; j++) h2[j] = fmaf(x2[k], W2[k * 16 + j], h2[j]);

    float x3[16];
#pragma unroll
    for (int j = 0; j < 16; j++) x3[j] = fmaxf(h2[j], 0.0f);
    float o[32];
#pragma unroll
    for (int j = 0; j < 32; j++) o[j] = B3[j];
#pragma unroll
    for (int k = 0; k < 16; k++)
#pragma unroll
        for (int j = 0; j < 32; j++)
            o[j] = fmaf(x3[k], W3[k * 32 + j], o[j]);

    if (e0 < n_edges) {
        float4* eo = (float4*)(edges_out + (size_t)e0 * 32);
#pragma unroll
        for (int j4 = 0; j4 < 8; j4++)
            eo[j4] = make_float4(o[j4 * 4 + 0], o[j4 * 4 + 1], o[j4 * 4 + 2], o[j4 * 4 + 3]);
    }
}

// -------- Receiver aggregation via CSR gather: 8 lanes per node -------------
__global__ __launch_bounds__(256)
void agg_mean_kernel(const float* __restrict__ edges_data,
                     const int* __restrict__ col_idx,
                     const int* __restrict__ row_ptr,
                     float* __restrict__ agg_mean, int n_nodes) {
    int node = blockIdx.x * 32 + (threadIdx.x >> 3);
    int lane = threadIdx.x & 7;
    if (node >= n_nodes) return;
    int lo = row_ptr[node], hi = row_ptr[node + 1];
    float4 acc = make_float4(0.f, 0.f, 0.f, 0.f);
    for (int e = lo; e < hi; e++) {
        int idx = col_idx[e];
        float4 v = ((const float4*)(edges_data + (size_t)idx * 32))[lane];
        acc.x += v.x; acc.y += v.y; acc.z += v.z; acc.w += v.w;
    }
    float inv = 1.0f / fmaxf((float)(hi - lo), 1.0f);
    ((float4*)(agg_mean + (size_t)node * 32))[lane] =
        make_float4(acc.x * inv, acc.y * inv, acc.z * inv, acc.w * inv);
}

// ---------------- Node block: 80 -> 16 -> 16 -> 32 --------------------------
__global__ __launch_bounds__(256)
void node_block_kernel(const float* __restrict__ agg_mean,
                       const float* __restrict__ nodes_in,
                       const float* __restrict__ glob_in,
                       const int* __restrict__ node_gid,
                       const float* __restrict__ W1, const float* __restrict__ B1,
                       const float* __restrict__ W2, const float* __restrict__ B2,
                       const float* __restrict__ W3, const float* __restrict__ B3,
                       float* __restrict__ nodes_out,
                       int n_nodes) {
    const int n0 = blockIdx.x * 256 + threadIdx.x;
    const int n  = min(n0, n_nodes - 1);
    const int gg = node_gid[n];

    const float4* pa = (const float4*)agg_mean + (size_t)n * 8;
    const float4* pn = (const float4*)nodes_in + (size_t)n * 8;
    const float4* pg = (const float4*)glob_in  + (size_t)gg * 4;

    float4 xa[8], xn[8], xg[4];
#pragma unroll
    for (int q = 0; q < 8; q++) xa[q] = pa[q];
#pragma unroll
    for (int q = 0; q < 8; q++) xn[q] = pn[q];
#pragma unroll
    for (int q = 0; q < 4; q++) xg[q] = pg[q];

    float h1[16];
#pragma unroll
    for (int j = 0; j < 16; j++) h1[j] = B1[j];
#pragma unroll
    for (int q = 0; q < 8; q++) fma4(h1, W1 + (q * 4) * 16, xa[q]);
#pragma unroll
    for (int q = 0; q < 8; q++) fma4(h1, W1 + (32 + q * 4) * 16, xn[q]);
#pragma unroll
    for (int q = 0; q < 4; q++) fma4(h1, W1 + (64 + q * 4) * 16, xg[q]);

    float x2[16];
#pragma unroll
    for (int j = 0; j < 16; j++) x2[j] = fmaxf(h1[j], 0.0f);
    float h2[16];
#pragma unroll
    for (int j = 0; j < 16; j++) h2[j] = B2[j];
#pragma unroll
    for (int k = 0; k < 16; k++)
#pragma unroll
        for (int j = 0; j < 16; j++) h2[j] = fmaf(x2[k], W2[k * 16 + j], h2[j]);

    float x3[16];
#pragma unroll
    for (int j = 0; j < 16; j++) x3[j] = fmaxf(h2[j], 0.0f);
    float o[32];
#pragma unroll
    for (int j = 0; j < 32; j++) o[j] = B3[j];
#pragma unroll
    for (int k = 0; k < 16; k++)
#pragma unroll
        for (int j = 0; j < 32; j++)
            o[j] = fmaf(x3[k], W3[k * 32 + j], o[j]);

    if (n0 < n_nodes) {
        float4* no = (float4*)(nodes_out + (size_t)n0 * 32);
#pragma unroll
        for (int j4 = 0; j4 < 8; j4++)
            no[j4] = make_float4(o[j4 * 4 + 0], o[j4 * 4 + 1], o[j4 * 4 + 2], o[j4 * 4 + 3]);
    }
}

// ---------------- Per-graph sums over sorted gid ranges ---------------------
__global__ __launch_bounds__(256)
void graph_sum_kernel(const float* __restrict__ x, const int* __restrict__ gid,
                      int n_rows, float* __restrict__ sums, int splits) {
    int g = blockIdx.x / splits;
    int s = blockIdx.x % splits;
    int lo = lower_bound_i(gid, n_rows, g);
    int hi = lower_bound_i(gid, n_rows, g + 1);
    int len = hi - lo;
    int chunk = (len + splits - 1) / splits;
    int rlo = lo + s * chunk;
    int rhi = min(rlo + chunk, hi);

    int c = threadIdx.x & 31;
    int rg = threadIdx.x >> 5;   // 8 row-groups with 256 threads
    float acc = 0.0f;
    for (int r = rlo + rg; r < rhi; r += 8)
        acc += x[(size_t)r * 32 + c];

    __shared__ float red[256];
    red[threadIdx.x] = acc;
    __syncthreads();
    if (threadIdx.x < 32) {
        float ssum = 0.0f;
#pragma unroll
        for (int i = 0; i < 8; i++) ssum += red[i * 32 + threadIdx.x];
        atomicAdd(&sums[g * 32 + threadIdx.x], ssum);
    }
}

// ---------------- Global block: 80 -> 16 -> 16 -> 16 ------------------------
__global__ __launch_bounds__(64)
void global_block_kernel(const float* __restrict__ gsum_e,
                         const float* __restrict__ gsum_n,
                         const float* __restrict__ glob_in,
                         const int* __restrict__ edge_gid, int n_edges,
                         const int* __restrict__ node_gid, int n_nodes,
                         const float* __restrict__ W1, const float* __restrict__ B1,
                         const float* __restrict__ W2, const float* __restrict__ B2,
                         const float* __restrict__ W3, const float* __restrict__ B3,
                         float* __restrict__ glob_out, int n_graph) {
    const int g0 = threadIdx.x;
    const int g  = min(g0, n_graph - 1);

    int ecnt = lower_bound_i(edge_gid, n_edges, g + 1) - lower_bound_i(edge_gid, n_edges, g);
    int ncnt = lower_bound_i(node_gid, n_nodes, g + 1) - lower_bound_i(node_gid, n_nodes, g);
    float inv_e = 1.0f / fmaxf((float)ecnt, 1.0f);
    float inv_n = 1.0f / fmaxf((float)ncnt, 1.0f);

    float h1[16];
#pragma unroll
    for (int j = 0; j < 16; j++) h1[j] = B1[j];

    {
        float x[32];
#pragma unroll
        for (int q = 0; q < 8; q++) {
            float4 v = ((const float4*)gsum_e)[(size_t)g * 8 + q];
            x[q*4+0] = v.x * inv_e; x[q*4+1] = v.y * inv_e; x[q*4+2] = v.z * inv_e; x[q*4+3] = v.w * inv_e;
        }
#pragma unroll
        for (int k = 0; k < 32; k++)
#pragma unroll
            for (int j = 0; j < 16; j++) h1[j] = fmaf(x[k], W1[k * 16 + j], h1[j]);
#pragma unroll
        for (int q = 0; q < 8; q++) {
            float4 v = ((const float4*)gsum_n)[(size_t)g * 8 + q];
            x[q*4+0] = v.x * inv_n; x[q*4+1] = v.y * inv_n; x[q*4+2] = v.z * inv_n; x[q*4+3] = v.w * inv_n;
        }
#pragma unroll
        for (int k = 0; k < 32; k++)
#pragma unroll
            for (int j = 0; j < 16; j++) h1[j] = fmaf(x[k], W1[(32 + k) * 16 + j], h1[j]);
    }
    {
        float xg[16];
#pragma unroll
        for (int q = 0; q < 4; q++) {
            float4 v = ((const float4*)glob_in)[(size_t)g * 4 + q];
            xg[q*4+0] = v.x; xg[q*4+1] = v.y; xg[q*4+2] = v.z; xg[q*4+3] = v.w;
        }
#pragma unroll
        for (int k = 0; k < 16; k++)
#pragma unroll
            for (int j = 0; j < 16; j++) h1[j] = fmaf(xg[k], W1[(64 + k) * 16 + j], h1[j]);
    }

    float x2[16];
#pragma unroll
    for (int j = 0; j < 16; j++) x2[j] = fmaxf(h1[j], 0.0f);
    float h2[16];
#pragma unroll
    for (int j = 0; j < 16; j++) h2[j] = B2[j];
#pragma unroll
    for (int k = 0; k < 16; k++)
#pragma unroll
        for (int j = 0; j < 16; j++) h2[j] = fmaf(x2[k], W2[k * 16 + j], h2[j]);

    float x3[16];
#pragma unroll
    for (int j = 0; j < 16; j++) x3[j] = fmaxf(h2[j], 0.0f);
    float o[16];
#pragma unroll
    for (int j = 0; j < 16; j++) o[j] = B3[j];
#pragma unroll
    for (int k = 0; k < 16; k++)
#pragma unroll
        for (int j = 0; j < 16; j++) o[j] = fmaf(x3[k], W3[k * 16 + j], o[j]);

    if (g0 < n_graph) {
#pragma unroll
        for (int j = 0; j < 16; j++) glob_out[g0 * 16 + j] = o[j];
    }
}

extern "C" void kernel_launch(void* const* d_in, const int* in_sizes, int n_in,
                              void* d_out, int out_size, void* d_ws, size_t ws_size,
                              hipStream_t stream) {
    const float* d_nodes = (const float*)d_in[0];
    const float* d_edges = (const float*)d_in[1];
    const float* d_glob  = (const float*)d_in[2];
    const int* senders   = (const int*)d_in[3];
    const int* receivers = (const int*)d_in[4];
    const int* node_gid  = (const int*)d_in[5];
    const int* edge_gid  = (const int*)d_in[6];
    const float* e_w1 = (const float*)d_in[7];
    const float* e_b1 = (const float*)d_in[8];
    const float* e_w2 = (const float*)d_in[9];
    const float* e_b2 = (const float*)d_in[10];
    const float* e_w3 = (const float*)d_in[11];
    const float* e_b3 = (const float*)d_in[12];
    const float* n_w1 = (const float*)d_in[13];
    const float* n_b1 = (const float*)d_in[14];
    const float* n_w2 = (const float*)d_in[15];
    const float* n_b2 = (const float*)d_in[16];
    const float* n_w3 = (const float*)d_in[17];
    const float* n_b3 = (const float*)d_in[18];
    const float* g_w1 = (const float*)d_in[19];
    const float* g_b1 = (const float*)d_in[20];
    const float* g_w2 = (const float*)d_in[21];
    const float* g_b2 = (const float*)d_in[22];
    const float* g_w3 = (const float*)d_in[23];
    const float* g_b3 = (const float*)d_in[24];

    const int n_nodes = in_sizes[0] / 32;
    const int n_edges = in_sizes[1] / 32;
    const int n_graph = in_sizes[2] / 16;

    float* out_nodes = (float*)d_out;                        // n_nodes*32
    float* out_edges = out_nodes + (size_t)n_nodes * 32;     // n_edges*32
    float* out_glob  = out_edges + (size_t)n_edges * 32;     // n_graph*16

    float* ws = (float*)d_ws;
    float* ws_edges = ws;  ws += (size_t)n_edges * 32;
    float* ws_nodes = ws;  ws += (size_t)n_nodes * 32;
    float* agg_mean = ws;  ws += (size_t)n_nodes * 32;
    float* gA       = ws;  ws += (size_t)n_graph * 16;
    float* gB       = ws;  ws += (size_t)n_graph * 16;
    float* gsum_e   = ws;  ws += (size_t)n_graph * 32;
    float* gsum_n   = ws;  ws += (size_t)n_graph * 32;

    int* wi = (int*)ws;
    int* cnt      = wi;  wi += n_nodes;
    int* row_ptr  = wi;  wi += n_nodes + 1;
    int* running  = wi;  wi += n_nodes;
    int* scan_tmp = wi;  wi += n_nodes;
    int* col_idx  = wi;  wi += n_edges;
    int* blk_sum  = wi;  wi += 1024;
    int* blk_off  = wi;  wi += 1024;

    const int nblocks_scan = (n_nodes + SCAN_B - 1) / SCAN_B;

    // ---- CSR build (receivers constant across passes) ----
    hipMemsetAsync(cnt, 0, (size_t)n_nodes * sizeof(int), stream);
    hist_kernel<<<(n_edges + 255) / 256, 256, 0, stream>>>(receivers, n_edges, cnt);
    scan_block_kernel<<<nblocks_scan, SCAN_B, 0, stream>>>(cnt, n_nodes, scan_tmp, blk_sum);
    scan_top_kernel<<<1, 1024, 0, stream>>>(blk_sum, nblocks_scan, blk_off);
    scan_finalize_kernel<<<nblocks_scan, SCAN_B, 0, stream>>>(cnt, scan_tmp, blk_off,
                                                              n_nodes, row_ptr, running);
    fill_kernel<<<(n_edges + 255) / 256, 256, 0, stream>>>(receivers, n_edges, running, col_idx);

    const float* nodes_in = d_nodes;
    const float* edges_in = d_edges;
    const float* glob_in  = d_glob;

    for (int pass = 0; pass < 3; ++pass) {
        float* nodes_out; float* edges_out; float* glob_out;
        if (pass == 0)      { nodes_out = out_nodes; edges_out = out_edges; glob_out = gA; }
        else if (pass == 1) { nodes_out = ws_nodes;  edges_out = ws_edges;  glob_out = gB; }
        else                { nodes_out = out_nodes; edges_out = out_edges; glob_out = out_glob; }

        hipMemsetAsync(gsum_e, 0, (size_t)n_graph * 32 * sizeof(float), stream);
        hipMemsetAsync(gsum_n, 0, (size_t)n_graph * 32 * sizeof(float), stream);

        edge_block_kernel<<<(n_edges + 255) / 256, 256, 0, stream>>>(
            edges_in, nodes_in, glob_in, senders, receivers, edge_gid,
            e_w1, e_b1, e_w2, e_b2, e_w3, e_b3,
            edges_out, n_edges);

        graph_sum_kernel<<<n_graph * 16, 256, 0, stream>>>(edges_out, edge_gid, n_edges, gsum_e, 16);

        agg_mean_kernel<<<(n_nodes + 31) / 32, 256, 0, stream>>>(
            edges_out, col_idx, row_ptr, agg_mean, n_nodes);

        node_block_kernel<<<(n_nodes + 255) / 256, 256, 0, stream>>>(
            agg_mean, nodes_in, glob_in, node_gid,
            n_w1, n_b1, n_w2, n_b2, n_w3, n_b3,
            nodes_out, n_nodes);

        graph_sum_kernel<<<n_graph * 4, 256, 0, stream>>>(nodes_out, node_gid, n_nodes, gsum_n, 4);

        global_block_kernel<<<1, 64, 0, stream>>>(
            gsum_e, gsum_n, glob_in, edge_gid, n_edges, node_gid, n_nodes,
            g_w1, g_b1, g_w2, g_b2, g_w3, g_b3,
            glob_out, n_graph);

        nodes_in = nodes_out;
        edges_in = edges_out;
        glob_in  = glob_out;
    }
}

// Round 7
// 843.499 us; speedup vs baseline: 5.5936x; 1.0940x over previous
//
#include <hip/hip_runtime.h>

#define DEV_INLINE __device__ __forceinline__

static const int SCAN_B = 512;

DEV_INLINE int lower_bound_i(const int* __restrict__ a, int n, int v) {
    int lo = 0, hi = n;
    while (lo < hi) { int m = (lo + hi) >> 1; if (a[m] < v) lo = m + 1; else hi = m; }
    return lo;
}

// h[0:16] += 4 features (a.x..a.w) * W rows (wave-uniform W -> scalar loads)
DEV_INLINE void fma4(float (&h)[16], const float* __restrict__ W, float4 a) {
#pragma unroll
    for (int j = 0; j < 16; j++) h[j] = fmaf(a.x, W[0 * 16 + j], h[j]);
#pragma unroll
    for (int j = 0; j < 16; j++) h[j] = fmaf(a.y, W[1 * 16 + j], h[j]);
#pragma unroll
    for (int j = 0; j < 16; j++) h[j] = fmaf(a.z, W[2 * 16 + j], h[j]);
#pragma unroll
    for (int j = 0; j < 16; j++) h[j] = fmaf(a.w, W[3 * 16 + j], h[j]);
}

// ========================= CSR build (once per launch) ======================
__global__ void hist_kernel(const int* __restrict__ receivers, int n_edges,
                            int* __restrict__ cnt) {
    int i = blockIdx.x * blockDim.x + threadIdx.x;
    if (i < n_edges) atomicAdd(&cnt[receivers[i]], 1);
}

__global__ __launch_bounds__(SCAN_B)
void scan_block_kernel(const int* __restrict__ cnt, int n,
                       int* __restrict__ scan_tmp, int* __restrict__ blk_sum) {
    __shared__ int s[SCAN_B];
    int tid = threadIdx.x;
    int i = blockIdx.x * SCAN_B + tid;
    int v = (i < n) ? cnt[i] : 0;
    s[tid] = v;
    __syncthreads();
    for (int off = 1; off < SCAN_B; off <<= 1) {
        int t = (tid >= off) ? s[tid - off] : 0;
        __syncthreads();
        s[tid] += t;
        __syncthreads();
    }
    if (i < n) scan_tmp[i] = s[tid];
    if (tid == SCAN_B - 1) blk_sum[blockIdx.x] = s[tid];
}

__global__ __launch_bounds__(1024)
void scan_top_kernel(int* __restrict__ blk_sum, int nb, int* __restrict__ blk_off) {
    __shared__ int s[1024];
    int tid = threadIdx.x;
    int v = (tid < nb) ? blk_sum[tid] : 0;
    s[tid] = v;
    __syncthreads();
    for (int off = 1; off < 1024; off <<= 1) {
        int t = (tid >= off) ? s[tid - off] : 0;
        __syncthreads();
        s[tid] += t;
        __syncthreads();
    }
    if (tid < nb) blk_off[tid] = s[tid] - v;   // exclusive
}

__global__ __launch_bounds__(SCAN_B)
void scan_finalize_kernel(const int* __restrict__ cnt, const int* __restrict__ scan_tmp,
                          const int* __restrict__ blk_off, int n,
                          int* __restrict__ row_ptr, int* __restrict__ running) {
    int i = blockIdx.x * SCAN_B + threadIdx.x;
    if (i >= n) return;
    int incl = scan_tmp[i] + blk_off[i / SCAN_B];
    row_ptr[i + 1] = incl;
    running[i] = incl - cnt[i];
    if (i == 0) row_ptr[0] = 0;
}

__global__ void fill_kernel(const int* __restrict__ receivers, int n_edges,
                            int* __restrict__ running, int* __restrict__ col_idx) {
    int e = blockIdx.x * blockDim.x + threadIdx.x;
    if (e >= n_edges) return;
    int pos = atomicAdd(&running[receivers[e]], 1);
    col_idx[pos] = e;
}

// ---- Per-pass precompute: node projections through edge-MLP layer-1 --------
// proj[n][0:16]  = W1[rows 32..63]  . nodes[n]   (receiver term)
// proj[n][16:32] = W1[rows 64..95]  . nodes[n]   (sender term)
__global__ __launch_bounds__(256)
void node_proj_kernel(const float* __restrict__ nodes_in,
                      const float* __restrict__ W1,
                      float* __restrict__ proj, int n_nodes) {
    const int n0 = blockIdx.x * 256 + threadIdx.x;
    const int n  = min(n0, n_nodes - 1);
    const float4* pn = (const float4*)nodes_in + (size_t)n * 8;
    float4 xn[8];
#pragma unroll
    for (int q = 0; q < 8; q++) xn[q] = pn[q];

    float hr[16], hs[16];
#pragma unroll
    for (int j = 0; j < 16; j++) { hr[j] = 0.0f; hs[j] = 0.0f; }
#pragma unroll
    for (int q = 0; q < 8; q++) fma4(hr, W1 + (32 + q * 4) * 16, xn[q]);
#pragma unroll
    for (int q = 0; q < 8; q++) fma4(hs, W1 + (64 + q * 4) * 16, xn[q]);

    if (n0 < n_nodes) {
        float4* po = (float4*)(proj + (size_t)n0 * 32);
#pragma unroll
        for (int j4 = 0; j4 < 4; j4++)
            po[j4] = make_float4(hr[j4*4+0], hr[j4*4+1], hr[j4*4+2], hr[j4*4+3]);
#pragma unroll
        for (int j4 = 0; j4 < 4; j4++)
            po[4 + j4] = make_float4(hs[j4*4+0], hs[j4*4+1], hs[j4*4+2], hs[j4*4+3]);
    }
}

// ---- Per-pass precompute: fold globals term + b1 into per-graph bias -------
__global__ __launch_bounds__(64)
void bias_kernel(const float* __restrict__ glob_in,
                 const float* __restrict__ eW1, const float* __restrict__ eB1,
                 const float* __restrict__ nW1, const float* __restrict__ nB1,
                 float* __restrict__ biasE, float* __restrict__ biasN, int n_graph) {
    const int g0 = threadIdx.x;
    const int g  = min(g0, n_graph - 1);
    float xg[16];
#pragma unroll
    for (int q = 0; q < 4; q++) {
        float4 v = ((const float4*)glob_in)[(size_t)g * 4 + q];
        xg[q*4+0] = v.x; xg[q*4+1] = v.y; xg[q*4+2] = v.z; xg[q*4+3] = v.w;
    }
    float he[16], hn[16];
#pragma unroll
    for (int j = 0; j < 16; j++) { he[j] = eB1[j]; hn[j] = nB1[j]; }
#pragma unroll
    for (int k = 0; k < 16; k++)
#pragma unroll
        for (int j = 0; j < 16; j++) he[j] = fmaf(xg[k], eW1[(96 + k) * 16 + j], he[j]);
#pragma unroll
    for (int k = 0; k < 16; k++)
#pragma unroll
        for (int j = 0; j < 16; j++) hn[j] = fmaf(xg[k], nW1[(64 + k) * 16 + j], hn[j]);
    if (g0 < n_graph) {
#pragma unroll
        for (int j = 0; j < 16; j++) biasE[g0 * 16 + j] = he[j];
#pragma unroll
        for (int j = 0; j < 16; j++) biasN[g0 * 16 + j] = hn[j];
    }
}

// ---------------- Edge block: 112 -> 16 -> 16 -> 32 (projected) -------------
// h1 = biasE[gid] + proj_r[recv] + proj_s[send] + W1e . edge_feat
__global__ __launch_bounds__(256)
void edge_block_kernel(const float* __restrict__ edges_in,
                       const float* __restrict__ proj,
                       const float* __restrict__ biasE,
                       const int* __restrict__ senders,
                       const int* __restrict__ receivers,
                       const int* __restrict__ edge_gid,
                       const float* __restrict__ W1,
                       const float* __restrict__ W2, const float* __restrict__ B2,
                       const float* __restrict__ W3, const float* __restrict__ B3,
                       float* __restrict__ edges_out,
                       int n_edges) {
    const int e0 = blockIdx.x * 256 + threadIdx.x;
    const int e  = min(e0, n_edges - 1);

    const int rr = receivers[e], ss = senders[e], gg = edge_gid[e];

    const float4* pe = (const float4*)edges_in + (size_t)e  * 8;
    const float4* pr = (const float4*)proj + (size_t)rr * 8;       // [0:4)
    const float4* ps = (const float4*)proj + (size_t)ss * 8 + 4;   // [4:8)
    const float4* pb = (const float4*)biasE + (size_t)gg * 4;

    float4 xe[8], xr[4], xs[4], xb[4];
#pragma unroll
    for (int q = 0; q < 8; q++) xe[q] = pe[q];
#pragma unroll
    for (int q = 0; q < 4; q++) xr[q] = pr[q];
#pragma unroll
    for (int q = 0; q < 4; q++) xs[q] = ps[q];
#pragma unroll
    for (int q = 0; q < 4; q++) xb[q] = pb[q];

    float h1[16];
#pragma unroll
    for (int q = 0; q < 4; q++) {
        h1[q*4+0] = xb[q].x + xr[q].x + xs[q].x;
        h1[q*4+1] = xb[q].y + xr[q].y + xs[q].y;
        h1[q*4+2] = xb[q].z + xr[q].z + xs[q].z;
        h1[q*4+3] = xb[q].w + xr[q].w + xs[q].w;
    }
#pragma unroll
    for (int q = 0; q < 8; q++) fma4(h1, W1 + (q * 4) * 16, xe[q]);

    float x2[16];
#pragma unroll
    for (int j = 0; j < 16; j++) x2[j] = fmaxf(h1[j], 0.0f);
    float h2[16];
#pragma unroll
    for (int j = 0; j < 16; j++) h2[j] = B2[j];
#pragma unroll
    for (int k = 0; k < 16; k++)
#pragma unroll
        for (int j = 0; j < 16; j++) h2[j] = fmaf(x2[k], W2[k * 16 + j], h2[j]);

    float x3[16];
#pragma unroll
    for (int j = 0; j < 16; j++) x3[j] = fmaxf(h2[j], 0.0f);
    float o[32];
#pragma unroll
    for (int j = 0; j < 32; j++) o[j] = B3[j];
#pragma unroll
    for (int k = 0; k < 16; k++)
#pragma unroll
        for (int j = 0; j < 32; j++)
            o[j] = fmaf(x3[k], W3[k * 32 + j], o[j]);

    if (e0 < n_edges) {
        float4* eo = (float4*)(edges_out + (size_t)e0 * 32);
#pragma unroll
        for (int j4 = 0; j4 < 8; j4++)
            eo[j4] = make_float4(o[j4 * 4 + 0], o[j4 * 4 + 1], o[j4 * 4 + 2], o[j4 * 4 + 3]);
    }
}

// -------- Receiver aggregation via CSR gather: 8 lanes per node -------------
__global__ __launch_bounds__(256)
void agg_mean_kernel(const float* __restrict__ edges_data,
                     const int* __restrict__ col_idx,
                     const int* __restrict__ row_ptr,
                     float* __restrict__ agg_mean, int n_nodes) {
    int node = blockIdx.x * 32 + (threadIdx.x >> 3);
    int lane = threadIdx.x & 7;
    if (node >= n_nodes) return;
    int lo = row_ptr[node], hi = row_ptr[node + 1];
    float4 acc = make_float4(0.f, 0.f, 0.f, 0.f);
    for (int e = lo; e < hi; e++) {
        int idx = col_idx[e];
        float4 v = ((const float4*)(edges_data + (size_t)idx * 32))[lane];
        acc.x += v.x; acc.y += v.y; acc.z += v.z; acc.w += v.w;
    }
    float inv = 1.0f / fmaxf((float)(hi - lo), 1.0f);
    ((float4*)(agg_mean + (size_t)node * 32))[lane] =
        make_float4(acc.x * inv, acc.y * inv, acc.z * inv, acc.w * inv);
}

// ---------------- Node block: 80 -> 16 -> 16 -> 32 --------------------------
// h1 = biasN[gid] + W1a . agg + W1n . node
__global__ __launch_bounds__(256)
void node_block_kernel(const float* __restrict__ agg_mean,
                       const float* __restrict__ nodes_in,
                       const float* __restrict__ biasN,
                       const int* __restrict__ node_gid,
                       const float* __restrict__ W1,
                       const float* __restrict__ W2, const float* __restrict__ B2,
                       const float* __restrict__ W3, const float* __restrict__ B3,
                       float* __restrict__ nodes_out,
                       int n_nodes) {
    const int n0 = blockIdx.x * 256 + threadIdx.x;
    const int n  = min(n0, n_nodes - 1);
    const int gg = node_gid[n];

    const float4* pa = (const float4*)agg_mean + (size_t)n * 8;
    const float4* pn = (const float4*)nodes_in + (size_t)n * 8;
    const float4* pb = (const float4*)biasN + (size_t)gg * 4;

    float4 xa[8], xn[8], xb[4];
#pragma unroll
    for (int q = 0; q < 8; q++) xa[q] = pa[q];
#pragma unroll
    for (int q = 0; q < 8; q++) xn[q] = pn[q];
#pragma unroll
    for (int q = 0; q < 4; q++) xb[q] = pb[q];

    float h1[16];
#pragma unroll
    for (int q = 0; q < 4; q++) {
        h1[q*4+0] = xb[q].x; h1[q*4+1] = xb[q].y; h1[q*4+2] = xb[q].z; h1[q*4+3] = xb[q].w;
    }
#pragma unroll
    for (int q = 0; q < 8; q++) fma4(h1, W1 + (q * 4) * 16, xa[q]);
#pragma unroll
    for (int q = 0; q < 8; q++) fma4(h1, W1 + (32 + q * 4) * 16, xn[q]);

    float x2[16];
#pragma unroll
    for (int j = 0; j < 16; j++) x2[j] = fmaxf(h1[j], 0.0f);
    float h2[16];
#pragma unroll
    for (int j = 0; j < 16; j++) h2[j] = B2[j];
#pragma unroll
    for (int k = 0; k < 16; k++)
#pragma unroll
        for (int j = 0; j < 16; j++) h2[j] = fmaf(x2[k], W2[k * 16 + j], h2[j]);

    float x3[16];
#pragma unroll
    for (int j = 0; j < 16; j++) x3[j] = fmaxf(h2[j], 0.0f);
    float o[32];
#pragma unroll
    for (int j = 0; j < 32; j++) o[j] = B3[j];
#pragma unroll
    for (int k = 0; k < 16; k++)
#pragma unroll
        for (int j = 0; j < 32; j++)
            o[j] = fmaf(x3[k], W3[k * 32 + j], o[j]);

    if (n0 < n_nodes) {
        float4* no = (float4*)(nodes_out + (size_t)n0 * 32);
#pragma unroll
        for (int j4 = 0; j4 < 8; j4++)
            no[j4] = make_float4(o[j4 * 4 + 0], o[j4 * 4 + 1], o[j4 * 4 + 2], o[j4 * 4 + 3]);
    }
}

// ---------------- Per-graph sums over sorted gid ranges ---------------------
__global__ __launch_bounds__(256)
void graph_sum_kernel(const float* __restrict__ x, const int* __restrict__ gid,
                      int n_rows, float* __restrict__ sums, int splits) {
    int g = blockIdx.x / splits;
    int s = blockIdx.x % splits;
    int lo = lower_bound_i(gid, n_rows, g);
    int hi = lower_bound_i(gid, n_rows, g + 1);
    int len = hi - lo;
    int chunk = (len + splits - 1) / splits;
    int rlo = lo + s * chunk;
    int rhi = min(rlo + chunk, hi);

    int c = threadIdx.x & 31;
    int rg = threadIdx.x >> 5;   // 8 row-groups with 256 threads
    float acc = 0.0f;
    for (int r = rlo + rg; r < rhi; r += 8)
        acc += x[(size_t)r * 32 + c];

    __shared__ float red[256];
    red[threadIdx.x] = acc;
    __syncthreads();
    if (threadIdx.x < 32) {
        float ssum = 0.0f;
#pragma unroll
        for (int i = 0; i < 8; i++) ssum += red[i * 32 + threadIdx.x];
        atomicAdd(&sums[g * 32 + threadIdx.x], ssum);
    }
}

// ---------------- Global block: 80 -> 16 -> 16 -> 16 ------------------------
__global__ __launch_bounds__(64)
void global_block_kernel(const float* __restrict__ gsum_e,
                         const float* __restrict__ gsum_n,
                         const float* __restrict__ glob_in,
                         const int* __restrict__ edge_gid, int n_edges,
                         const int* __restrict__ node_gid, int n_nodes,
                         const float* __restrict__ W1, const float* __restrict__ B1,
                         const float* __restrict__ W2, const float* __restrict__ B2,
                         const float* __restrict__ W3, const float* __restrict__ B3,
                         float* __restrict__ glob_out, int n_graph) {
    const int g0 = threadIdx.x;
    const int g  = min(g0, n_graph - 1);

    int ecnt = lower_bound_i(edge_gid, n_edges, g + 1) - lower_bound_i(edge_gid, n_edges, g);
    int ncnt = lower_bound_i(node_gid, n_nodes, g + 1) - lower_bound_i(node_gid, n_nodes, g);
    float inv_e = 1.0f / fmaxf((float)ecnt, 1.0f);
    float inv_n = 1.0f / fmaxf((float)ncnt, 1.0f);

    float h1[16];
#pragma unroll
    for (int j = 0; j < 16; j++) h1[j] = B1[j];

    {
        float x[32];
#pragma unroll
        for (int q = 0; q < 8; q++) {
            float4 v = ((const float4*)gsum_e)[(size_t)g * 8 + q];
            x[q*4+0] = v.x * inv_e; x[q*4+1] = v.y * inv_e; x[q*4+2] = v.z * inv_e; x[q*4+3] = v.w * inv_e;
        }
#pragma unroll
        for (int k = 0; k < 32; k++)
#pragma unroll
            for (int j = 0; j < 16; j++) h1[j] = fmaf(x[k], W1[k * 16 + j], h1[j]);
#pragma unroll
        for (int q = 0; q < 8; q++) {
            float4 v = ((const float4*)gsum_n)[(size_t)g * 8 + q];
            x[q*4+0] = v.x * inv_n; x[q*4+1] = v.y * inv_n; x[q*4+2] = v.z * inv_n; x[q*4+3] = v.w * inv_n;
        }
#pragma unroll
        for (int k = 0; k < 32; k++)
#pragma unroll
            for (int j = 0; j < 16; j++) h1[j] = fmaf(x[k], W1[(32 + k) * 16 + j], h1[j]);
    }
    {
        float xg[16];
#pragma unroll
        for (int q = 0; q < 4; q++) {
            float4 v = ((const float4*)glob_in)[(size_t)g * 4 + q];
            xg[q*4+0] = v.x; xg[q*4+1] = v.y; xg[q*4+2] = v.z; xg[q*4+3] = v.w;
        }
#pragma unroll
        for (int k = 0; k < 16; k++)
#pragma unroll
            for (int j = 0; j < 16; j++) h1[j] = fmaf(xg[k], W1[(64 + k) * 16 + j], h1[j]);
    }

    float x2[16];
#pragma unroll
    for (int j = 0; j < 16; j++) x2[j] = fmaxf(h1[j], 0.0f);
    float h2[16];
#pragma unroll
    for (int j = 0; j < 16; j++) h2[j] = B2[j];
#pragma unroll
    for (int k = 0; k < 16; k++)
#pragma unroll
        for (int j = 0; j < 16; j++) h2[j] = fmaf(x2[k], W2[k * 16 + j], h2[j]);

    float x3[16];
#pragma unroll
    for (int j = 0; j < 16; j++) x3[j] = fmaxf(h2[j], 0.0f);
    float o[16];
#pragma unroll
    for (int j = 0; j < 16; j++) o[j] = B3[j];
#pragma unroll
    for (int k = 0; k < 16; k++)
#pragma unroll
        for (int j = 0; j < 16; j++) o[j] = fmaf(x3[k], W3[k * 16 + j], o[j]);

    if (g0 < n_graph) {
#pragma unroll
        for (int j = 0; j < 16; j++) glob_out[g0 * 16 + j] = o[j];
    }
}

extern "C" void kernel_launch(void* const* d_in, const int* in_sizes, int n_in,
                              void* d_out, int out_size, void* d_ws, size_t ws_size,
                              hipStream_t stream) {
    const float* d_nodes = (const float*)d_in[0];
    const float* d_edges = (const float*)d_in[1];
    const float* d_glob  = (const float*)d_in[2];
    const int* senders   = (const int*)d_in[3];
    const int* receivers = (const int*)d_in[4];
    const int* node_gid  = (const int*)d_in[5];
    const int* edge_gid  = (const int*)d_in[6];
    const float* e_w1 = (const float*)d_in[7];
    const float* e_b1 = (const float*)d_in[8];
    const float* e_w2 = (const float*)d_in[9];
    const float* e_b2 = (const float*)d_in[10];
    const float* e_w3 = (const float*)d_in[11];
    const float* e_b3 = (const float*)d_in[12];
    const float* n_w1 = (const float*)d_in[13];
    const float* n_b1 = (const float*)d_in[14];
    const float* n_w2 = (const float*)d_in[15];
    const float* n_b2 = (const float*)d_in[16];
    const float* n_w3 = (const float*)d_in[17];
    const float* n_b3 = (const float*)d_in[18];
    const float* g_w1 = (const float*)d_in[19];
    const float* g_b1 = (const float*)d_in[20];
    const float* g_w2 = (const float*)d_in[21];
    const float* g_b2 = (const float*)d_in[22];
    const float* g_w3 = (const float*)d_in[23];
    const float* g_b3 = (const float*)d_in[24];

    const int n_nodes = in_sizes[0] / 32;
    const int n_edges = in_sizes[1] / 32;
    const int n_graph = in_sizes[2] / 16;

    float* out_nodes = (float*)d_out;                        // n_nodes*32
    float* out_edges = out_nodes + (size_t)n_nodes * 32;     // n_edges*32
    float* out_glob  = out_edges + (size_t)n_edges * 32;     // n_graph*16

    float* ws = (float*)d_ws;
    float* ws_edges = ws;  ws += (size_t)n_edges * 32;
    float* ws_nodes = ws;  ws += (size_t)n_nodes * 32;
    float* nscratch = ws;  ws += (size_t)n_nodes * 32;   // proj THEN agg_mean (disjoint lifetimes)
    float* gA       = ws;  ws += (size_t)n_graph * 16;
    float* gB       = ws;  ws += (size_t)n_graph * 16;
    float* gsum_e   = ws;  ws += (size_t)n_graph * 32;
    float* gsum_n   = ws;  ws += (size_t)n_graph * 32;
    float* biasE    = ws;  ws += (size_t)n_graph * 16;
    float* biasN    = ws;  ws += (size_t)n_graph * 16;

    int* wi = (int*)ws;
    int* cnt      = wi;  wi += n_nodes;
    int* row_ptr  = wi;  wi += n_nodes + 1;
    int* running  = wi;  wi += n_nodes;
    int* scan_tmp = wi;  wi += n_nodes;
    int* col_idx  = wi;  wi += n_edges;
    int* blk_sum  = wi;  wi += 1024;
    int* blk_off  = wi;  wi += 1024;

    const int nblocks_scan = (n_nodes + SCAN_B - 1) / SCAN_B;

    // ---- CSR build (receivers constant across passes) ----
    hipMemsetAsync(cnt, 0, (size_t)n_nodes * sizeof(int), stream);
    hist_kernel<<<(n_edges + 255) / 256, 256, 0, stream>>>(receivers, n_edges, cnt);
    scan_block_kernel<<<nblocks_scan, SCAN_B, 0, stream>>>(cnt, n_nodes, scan_tmp, blk_sum);
    scan_top_kernel<<<1, 1024, 0, stream>>>(blk_sum, nblocks_scan, blk_off);
    scan_finalize_kernel<<<nblocks_scan, SCAN_B, 0, stream>>>(cnt, scan_tmp, blk_off,
                                                              n_nodes, row_ptr, running);
    fill_kernel<<<(n_edges + 255) / 256, 256, 0, stream>>>(receivers, n_edges, running, col_idx);

    const float* nodes_in = d_nodes;
    const float* edges_in = d_edges;
    const float* glob_in  = d_glob;

    for (int pass = 0; pass < 3; ++pass) {
        float* nodes_out; float* edges_out; float* glob_out;
        if (pass == 0)      { nodes_out = out_nodes; edges_out = out_edges; glob_out = gA; }
        else if (pass == 1) { nodes_out = ws_nodes;  edges_out = ws_edges;  glob_out = gB; }
        else                { nodes_out = out_nodes; edges_out = out_edges; glob_out = out_glob; }

        hipMemsetAsync(gsum_e, 0, (size_t)n_graph * 32 * sizeof(float), stream);
        hipMemsetAsync(gsum_n, 0, (size_t)n_graph * 32 * sizeof(float), stream);

        bias_kernel<<<1, 64, 0, stream>>>(glob_in, e_w1, e_b1, n_w1, n_b1,
                                          biasE, biasN, n_graph);
        node_proj_kernel<<<(n_nodes + 255) / 256, 256, 0, stream>>>(
            nodes_in, e_w1, nscratch, n_nodes);

        edge_block_kernel<<<(n_edges + 255) / 256, 256, 0, stream>>>(
            edges_in, nscratch, biasE, senders, receivers, edge_gid,
            e_w1, e_w2, e_b2, e_w3, e_b3,
            edges_out, n_edges);

        graph_sum_kernel<<<n_graph * 16, 256, 0, stream>>>(edges_out, edge_gid, n_edges, gsum_e, 16);

        agg_mean_kernel<<<(n_nodes + 31) / 32, 256, 0, stream>>>(
            edges_out, col_idx, row_ptr, nscratch, n_nodes);

        node_block_kernel<<<(n_nodes + 255) / 256, 256, 0, stream>>>(
            nscratch, nodes_in, biasN, node_gid,
            n_w1, n_w2, n_b2, n_w3, n_b3,
            nodes_out, n_nodes);

        graph_sum_kernel<<<n_graph * 4, 256, 0, stream>>>(nodes_out, node_gid, n_nodes, gsum_n, 4);

        global_block_kernel<<<1, 64, 0, stream>>>(
            gsum_e, gsum_n, glob_in, edge_gid, n_edges, node_gid, n_nodes,
            g_w1, g_b1, g_w2, g_b2, g_w3, g_b3,
            glob_out, n_graph);

        nodes_in = nodes_out;
        edges_in = edges_out;
        glob_in  = glob_out;
    }
}